// Round 6
// baseline (73.607 us; speedup 1.0000x reference)
//
#include <hip/hip_runtime.h>
#include <hip/hip_bf16.h>
#include <math.h>

#define B_ 8
#define S_ 2048
#define H_ 4
#define DH_ 32
#define D_ 128
#define BS_ (B_ * S_)
#define NT_ 32                     // S/64 KV tiles
#define LOG2E 1.4426950408889634f
#define QSCALE (0.17677669529663687f * LOG2E)

typedef float f32x4  __attribute__((ext_vector_type(4)));
typedef float f32x16 __attribute__((ext_vector_type(16)));
typedef short s16x8  __attribute__((ext_vector_type(8)));

__device__ __forceinline__ unsigned short bf(float x) {
    return __builtin_bit_cast(unsigned short, __float2bfloat16(x));
}
__device__ __forceinline__ float bf2f(unsigned short u) {
    return __builtin_bit_cast(float, (unsigned int)u << 16);
}
__device__ __forceinline__ unsigned int pk2(float a, float b) {
    return (unsigned int)bf(a) | ((unsigned int)bf(b) << 16);
}
// v_permlane32_swap_b32: a' = [a_hw0 | b_hw0], b' = [a_hw1 | b_hw1]
__device__ __forceinline__ void pswap(unsigned int& a, unsigned int& b) {
    asm volatile("v_permlane32_swap_b32 %0, %1" : "+v"(a), "+v"(b));
}

// ---------------------------------------------------------------------------
// Kernel 0: W -> Wt (transposed, split bf16 hi/lo) + Eml = mask*log2e (f32)
// grid (4,4,4), block 256. z<3: 32x32 W-tile transpose; z==3: Eml table.
// ---------------------------------------------------------------------------
__global__ __launch_bounds__(256) void wprep(
    const float* __restrict__ Wq, const float* __restrict__ Wk, const float* __restrict__ Wv,
    const float* __restrict__ maskg,
    unsigned short* __restrict__ Wt, float* __restrict__ Eml)
{
    if (blockIdx.z == 3) {
        const int id16 = blockIdx.y * 4 + blockIdx.x;
        const int base = id16 * 1024 + threadIdx.x * 4;
        float4 m4 = *(const float4*)&maskg[base];
        float4 o = make_float4(m4.x * LOG2E, m4.y * LOG2E, m4.z * LOG2E, m4.w * LOG2E);
        *(float4*)&Eml[base] = o;
        return;
    }
    const float* W = (blockIdx.z == 0) ? Wq : (blockIdx.z == 1) ? Wk : Wv;
    unsigned short* Oh = Wt + (size_t)blockIdx.z * D_ * D_;
    unsigned short* Ol = Oh + 3 * D_ * D_;
    __shared__ float tf[32][36];
    const int t = threadIdx.x;
    const int kt = blockIdx.x * 32, ct = blockIdx.y * 32;
    {
        int kl = t >> 3, cl = (t & 7) * 4;
        float4 w4 = *(const float4*)&W[(size_t)(kt + kl) * D_ + ct + cl];
        tf[kl][cl + 0] = w4.x; tf[kl][cl + 1] = w4.y;
        tf[kl][cl + 2] = w4.z; tf[kl][cl + 3] = w4.w;
    }
    __syncthreads();
    {
        int cl = t >> 3, kl = (t & 7) * 4;
        ushort4 oh, ol;
        float v;
        v = tf[kl + 0][cl]; oh.x = bf(v); ol.x = bf(v - bf2f(oh.x));
        v = tf[kl + 1][cl]; oh.y = bf(v); ol.y = bf(v - bf2f(oh.y));
        v = tf[kl + 2][cl]; oh.z = bf(v); ol.z = bf(v - bf2f(oh.z));
        v = tf[kl + 3][cl]; oh.w = bf(v); ol.w = bf(v - bf2f(oh.w));
        *(ushort4*)&Oh[(size_t)(ct + cl) * D_ + kt + kl] = oh;
        *(ushort4*)&Ol[(size_t)(ct + cl) * D_ + kt + kl] = ol;
    }
}

// ---------------------------------------------------------------------------
// Kernel 1: QKV projection via split-bf16 MFMA (3 terms == fp32 accuracy).
// Q pre-scaled by scale*log2e. Q/K out: [bh][s][32] bf16;
// V out TRANSPOSED: Vt[bh][d][s] bf16 (plain, no mask scale).
// grid (BS/32, 2 c-halves, 3 modes), block 256 = 4 waves.
// ---------------------------------------------------------------------------
__global__ __launch_bounds__(256) void qkv_mfma(
    const float* __restrict__ Xq, const float* __restrict__ Xk, const float* __restrict__ Xv,
    const unsigned short* __restrict__ Wt,
    const float* __restrict__ bq, const float* __restrict__ bk, const float* __restrict__ bv,
    unsigned short* __restrict__ Qo, unsigned short* __restrict__ Ko,
    unsigned short* __restrict__ Vt)
{
    const int mode = blockIdx.z, chalf = blockIdx.y;
    const float* X; const float* bias; unsigned short* O; float scl;
    if (mode == 0)      { X = Xq; bias = bq; O = Qo; scl = QSCALE; }
    else if (mode == 1) { X = Xk; bias = bk; O = Ko; scl = 1.f; }
    else                { X = Xv; bias = bv; O = Vt; scl = 1.f; }
    const unsigned short* WmH = Wt + (size_t)mode * D_ * D_;
    const unsigned short* WmL = WmH + 3 * D_ * D_;

    __shared__ __align__(16) unsigned short xa[2 * 32 * 136];   // X hi/lo; reused as bounce
    __shared__ __align__(16) unsigned short wt[2 * 64 * 136];   // Wt hi/lo, 64 c-rows

    const int t = threadIdx.x;
    const long row0 = (long)blockIdx.x * 32;

    #pragma unroll
    for (int j = 0; j < 8; j++) {
        int idx = t + 256 * j;
        int part = idx >> 10, i2 = idx & 1023;
        int r = i2 >> 4, c16 = i2 & 15;
        const unsigned short* src = part ? WmL : WmH;
        uint4 v = *(const uint4*)&src[(size_t)(chalf * 64 + r) * D_ + c16 * 8];
        *(uint4*)&wt[part * 8704 + r * 136 + c16 * 8] = v;
    }
    #pragma unroll
    for (int j = 0; j < 4; j++) {
        int idx = t + 256 * j;
        int r = idx >> 5, c4 = idx & 31;
        float4 v = *(const float4*)(X + (row0 + r) * D_ + c4 * 4);
        ushort4 ph, pl;
        ph.x = bf(v.x); pl.x = bf(v.x - bf2f(ph.x));
        ph.y = bf(v.y); pl.y = bf(v.y - bf2f(ph.y));
        ph.z = bf(v.z); pl.z = bf(v.z - bf2f(ph.z));
        ph.w = bf(v.w); pl.w = bf(v.w - bf2f(ph.w));
        *(ushort4*)&xa[r * 136 + c4 * 4] = ph;
        *(ushort4*)&xa[4352 + r * 136 + c4 * 4] = pl;
    }
    __syncthreads();

    const int w = t >> 6, lane = t & 63, lo = lane & 15, hi = lane >> 4;
    const int mf = w >> 1, nb = (w & 1) * 2;
    f32x4 acc[2] = {};
    #pragma unroll
    for (int kk = 0; kk < 4; kk++) {
        const int ko = kk * 32 + hi * 8;
        s16x8 ah = *(const s16x8*)&xa[(mf * 16 + lo) * 136 + ko];
        s16x8 al = *(const s16x8*)&xa[4352 + (mf * 16 + lo) * 136 + ko];
        #pragma unroll
        for (int n2 = 0; n2 < 2; n2++) {
            const int nf = nb + n2;
            s16x8 bh2 = *(const s16x8*)&wt[(nf * 16 + lo) * 136 + ko];
            s16x8 bl2 = *(const s16x8*)&wt[8704 + (nf * 16 + lo) * 136 + ko];
            acc[n2] = __builtin_amdgcn_mfma_f32_16x16x32_bf16(ah, bh2, acc[n2], 0, 0, 0);
            acc[n2] = __builtin_amdgcn_mfma_f32_16x16x32_bf16(al, bh2, acc[n2], 0, 0, 0);
            acc[n2] = __builtin_amdgcn_mfma_f32_16x16x32_bf16(ah, bl2, acc[n2], 0, 0, 0);
        }
    }
    __syncthreads();   // xa free for bounce

    if (mode < 2) {
        #pragma unroll
        for (int n2 = 0; n2 < 2; n2++) {
            int c_l = (nb + n2) * 16 + lo;
            float bb = bias[chalf * 64 + c_l];
            #pragma unroll
            for (int r = 0; r < 4; r++) {
                int s = mf * 16 + hi * 4 + r;
                xa[s * 72 + c_l] = bf((acc[n2][r] + bb) * scl);
            }
        }
        __syncthreads();
        int s = t >> 3, part = t & 7;
        int c_g = chalf * 64 + part * 8;
        int h = c_g >> 5, d = c_g & 31;
        long b_i = (row0 + s) >> 11, s_i = (row0 + s) & 2047;
        unsigned short* orow = O + ((b_i * H_ + h) * (long)S_ + s_i) * DH_ + d;
        *(uint4*)orow = *(const uint4*)&xa[s * 72 + part * 8];
    } else {
        const long b_i = row0 >> 11;
        const long s0g = row0 & 2047;
        #pragma unroll
        for (int n2 = 0; n2 < 2; n2++) {
            int c_l = (nb + n2) * 16 + lo;
            float bb = bias[chalf * 64 + c_l];
            #pragma unroll
            for (int r = 0; r < 4; r++) {
                int s = mf * 16 + hi * 4 + r;
                xa[c_l * 68 + s] = bf(acc[n2][r] + bb);
            }
        }
        __syncthreads();
        if (t < 128) {
            int c_l = t >> 1, sh2 = (t & 1) * 16;
            int c_g = chalf * 64 + c_l;
            int h = c_g >> 5, d = c_g & 31;
            long s_i = s0g + sh2;
            unsigned short* orow = O + ((b_i * H_ + h) * (long)DH_ + d) * S_ + s_i;
            uint2 p0 = *(const uint2*)&xa[c_l * 68 + sh2 + 0];
            uint2 p1 = *(const uint2*)&xa[c_l * 68 + sh2 + 4];
            uint2 p2 = *(const uint2*)&xa[c_l * 68 + sh2 + 8];
            uint2 p3 = *(const uint2*)&xa[c_l * 68 + sh2 + 12];
            *(uint4*)&orow[0] = make_uint4(p0.x, p0.y, p1.x, p1.y);
            *(uint4*)&orow[8] = make_uint4(p2.x, p2.y, p3.x, p3.y);
        }
    }
}

// ---------------------------------------------------------------------------
// Kernel 2: flash attention, 32x32x16 MFMA, P entirely in registers.
// grid 512 (XCD-grouped), block 256 = 4 waves, 32 q-rows/wave.
// Swapped QK^T (A=K from global regs, B=Q regs) -> lane holds 16 scores for
// q=l&31; mask-add (log2 domain) + exp2 + cvt_pk; 4 permlane32_swap build the
// PV A-frags in-register. V LDS-staged (double-buffered); l via MFMA vs ones
// (lands in ctx row layout). Only LDS traffic: V stage + 4 b128 reads/tile.
// ---------------------------------------------------------------------------
__global__ __launch_bounds__(256) void flash_mfma(
    const unsigned short* __restrict__ Qg, const unsigned short* __restrict__ Kg,
    const unsigned short* __restrict__ Vtg, const float* __restrict__ Eml,
    const float* __restrict__ head_mask, float* __restrict__ Out)
{
    __shared__ __align__(16) unsigned short vs[2][32][72];   // V^T [d][k], dbuf

    const int t = threadIdx.x, w = t >> 6, lane = t & 63;
    const int l31 = lane & 31, hw = lane >> 5;

    const int lid = blockIdx.x;
    const int xcd = lid & 7, ser = lid >> 3;
    const int bh = xcd + 8 * (ser >> 4);   // 4 bh per XCD
    const int qi = ser & 15;
    const int b = bh >> 2, h = bh & 3;

    const size_t kvbase = (size_t)bh * S_ * DH_;
    const size_t vtbase = (size_t)bh * DH_ * S_;
    const float* emlb = Eml + (size_t)b * S_;
    const int q0 = qi * 128 + w * 32;
    const float hm = head_mask[h];

    // Q fragments (B-operand): lane holds Q[q=q0+l31][dims h16*16 + hw*8 ..+8]
    const unsigned short* qp = Qg + kvbase + (size_t)(q0 + l31) * DH_ + hw * 8;
    const s16x8 qf0 = *(const s16x8*)qp;
    const s16x8 qf1 = *(const s16x8*)(qp + 16);

    // K fragments (A-operand) straight from global: K[key=kgrp*32+l31][dims]
    const unsigned short* kfp = Kg + kvbase + (size_t)l31 * DH_ + hw * 8;
    s16x8 kf00 = *(const s16x8*)(kfp);
    s16x8 kf01 = *(const s16x8*)(kfp + 16);
    s16x8 kf10 = *(const s16x8*)(kfp + 1024);
    s16x8 kf11 = *(const s16x8*)(kfp + 1040);

    // V staging: thread -> (d, key-chunk)
    const int vd = t >> 3, vk = (t & 7) * 8;
    *(uint4*)&vs[0][vd][vk] = *(const uint4*)(Vtg + vtbase + (size_t)vd * S_ + vk);
    __syncthreads();

    f32x16 ctx = {};
    f32x16 lacc = {};
    const f32x16 z16 = {};
    const s16x8 ones = {0x3F80, 0x3F80, 0x3F80, 0x3F80, 0x3F80, 0x3F80, 0x3F80, 0x3F80};

    for (int tile = 0; tile < NT_; tile++) {
        const int cur = tile & 1, nxt = cur ^ 1;

        // prefetch next tile: K frags -> regs, V -> reg (written to LDS later)
        s16x8 kn00, kn01, kn10, kn11; uint4 vreg;
        if (tile < NT_ - 1) {
            const unsigned short* kp2 = kfp + (size_t)(tile + 1) * 2048;
            kn00 = *(const s16x8*)(kp2);
            kn01 = *(const s16x8*)(kp2 + 16);
            kn10 = *(const s16x8*)(kp2 + 1024);
            kn11 = *(const s16x8*)(kp2 + 1040);
            vreg = *(const uint4*)(Vtg + vtbase + (size_t)vd * S_ + (tile + 1) * 64 + vk);
        }
        // mask (log2-domain) for this tile's keys: lane's keys 8g+4hw+(0..3)
        const float* emt = emlb + tile * 64 + hw * 4;
        f32x4 ea[4], eb[4];
        #pragma unroll
        for (int g = 0; g < 4; g++) {
            ea[g] = *(const f32x4*)(emt + g * 8);
            eb[g] = *(const f32x4*)(emt + 32 + g * 8);
        }

        #pragma unroll
        for (int kgrp = 0; kgrp < 2; kgrp++) {
            const s16x8 ka = kgrp ? kf10 : kf00;
            const s16x8 kb = kgrp ? kf11 : kf01;

            // ---- QK^T: S^T[key][q], exp2 domain (Q pre-scaled)
            __builtin_amdgcn_s_setprio(1);
            f32x16 s = __builtin_amdgcn_mfma_f32_32x32x16_bf16(ka, qf0, z16, 0, 0, 0);
            s = __builtin_amdgcn_mfma_f32_32x32x16_bf16(kb, qf1, s, 0, 0, 0);
            __builtin_amdgcn_s_setprio(0);

            // ---- P = exp2(s + m*log2e), pack to bf16 pairs
            unsigned int pd[8];
            #pragma unroll
            for (int j = 0; j < 8; j++) {
                const int r0 = 2 * j, r1 = 2 * j + 1;
                const float e0 = kgrp ? eb[r0 >> 2][r0 & 3] : ea[r0 >> 2][r0 & 3];
                const float e1 = kgrp ? eb[r1 >> 2][r1 & 3] : ea[r1 >> 2][r1 & 3];
                const float p0 = __builtin_amdgcn_exp2f(s[r0] + e0);
                const float p1 = __builtin_amdgcn_exp2f(s[r1] + e1);
                pd[j] = pk2(p0, p1);
            }
            // redistribute halves -> PV A-fragments, fully in-register
            pswap(pd[0], pd[2]); pswap(pd[1], pd[3]);
            pswap(pd[4], pd[6]); pswap(pd[5], pd[7]);
            const s16x8 pa0 = __builtin_bit_cast(s16x8, make_uint4(pd[0], pd[1], pd[2], pd[3]));
            const s16x8 pa1 = __builtin_bit_cast(s16x8, make_uint4(pd[4], pd[5], pd[6], pd[7]));

            // ---- PV + l
            __builtin_amdgcn_s_setprio(1);
            const s16x8 vb0 = *(const s16x8*)&vs[cur][l31][kgrp * 32 + hw * 8];
            ctx  = __builtin_amdgcn_mfma_f32_32x32x16_bf16(pa0, vb0, ctx, 0, 0, 0);
            lacc = __builtin_amdgcn_mfma_f32_32x32x16_bf16(pa0, ones, lacc, 0, 0, 0);
            const s16x8 vb1 = *(const s16x8*)&vs[cur][l31][kgrp * 32 + 16 + hw * 8];
            ctx  = __builtin_amdgcn_mfma_f32_32x32x16_bf16(pa1, vb1, ctx, 0, 0, 0);
            lacc = __builtin_amdgcn_mfma_f32_32x32x16_bf16(pa1, ones, lacc, 0, 0, 0);
            __builtin_amdgcn_s_setprio(0);
        }

        if (tile < NT_ - 1) {
            *(uint4*)&vs[nxt][vd][vk] = vreg;
            __syncthreads();
            kf00 = kn00; kf01 = kn01; kf10 = kn10; kf11 = kn11;
        }
    }

    // ---- epilogue: out = ctx * head_mask / l  (lacc already row-aligned)
    #pragma unroll
    for (int r = 0; r < 16; r++) {
        const int qrow = (r & 3) + 8 * (r >> 2) + 4 * hw;
        const float inv = hm / lacc[r];
        Out[((size_t)b * S_ + q0 + qrow) * D_ + h * DH_ + l31] = ctx[r] * inv;
    }
}

// ---------------------------------------------------------------------------
extern "C" void kernel_launch(void* const* d_in, const int* in_sizes, int n_in,
                              void* d_out, int out_size, void* d_ws, size_t ws_size,
                              hipStream_t stream) {
    const float* Xq   = (const float*)d_in[0];
    const float* Xk   = (const float*)d_in[1];
    const float* Xv   = (const float*)d_in[2];
    const float* mask = (const float*)d_in[3];
    const float* hm   = (const float*)d_in[4];
    const float* Wq   = (const float*)d_in[5];
    const float* bq   = (const float*)d_in[6];
    const float* Wk   = (const float*)d_in[7];
    const float* bk   = (const float*)d_in[8];
    const float* Wv   = (const float*)d_in[9];
    const float* bv   = (const float*)d_in[10];
    float* out = (float*)d_out;

    unsigned short* Qo = (unsigned short*)d_ws;             // [bh][s][32] bf16
    unsigned short* Ko = Qo + (size_t)2097152;              // [bh][s][32] bf16
    unsigned short* Vt = Ko + (size_t)2097152;              // [bh][d][s]  bf16
    unsigned short* Wt = Vt + (size_t)2097152;              // [2][3][128][128]
    float*          Eml = (float*)((char*)d_ws + 12779520); // [b][s] f32 mask*log2e

    wprep<<<dim3(4, 4, 4), 256, 0, stream>>>(Wq, Wk, Wv, mask, Wt, Eml);
    qkv_mfma<<<dim3(BS_ / 32, 2, 3), 256, 0, stream>>>(Xq, Xk, Xv, Wt, bq, bk, bv, Qo, Ko, Vt);
    flash_mfma<<<dim3(512), 256, 0, stream>>>(Qo, Ko, Vt, Eml, hm, out);
}

// Round 8
// 54.607 us; speedup vs baseline: 1.3479x; 1.3479x over previous
//
#include <hip/hip_runtime.h>
#include <hip/hip_bf16.h>
#include <math.h>

#define B_ 8
#define S_ 2048
#define H_ 4
#define DH_ 32
#define D_ 128
#define BS_ (B_ * S_)
#define LOG2E 1.4426950408889634f
#define QSCALE (0.17677669529663687f * LOG2E)

typedef float f32x4  __attribute__((ext_vector_type(4)));
typedef float f32x16 __attribute__((ext_vector_type(16)));
typedef short s16x8  __attribute__((ext_vector_type(8)));

__device__ __forceinline__ unsigned short bf(float x) {
    return __builtin_bit_cast(unsigned short, __float2bfloat16(x));
}
__device__ __forceinline__ float bf2f(unsigned short u) {
    return __builtin_bit_cast(float, (unsigned int)u << 16);
}
// v_cvt_pk_bf16_f32: dst.lo = bf16(a), dst.hi = bf16(b)  (1 VALU instr)
__device__ __forceinline__ unsigned int pk2(float a, float b) {
    unsigned int r;
    asm("v_cvt_pk_bf16_f32 %0, %1, %2" : "=v"(r) : "v"(a), "v"(b));
    return r;
}
// v_permlane32_swap_b32: a' = [a_lo | b_lo], b' = [a_hi | b_hi]
__device__ __forceinline__ void pswap(unsigned int& a, unsigned int& b) {
    asm volatile("v_permlane32_swap_b32 %0, %1" : "+v"(a), "+v"(b));
}

// ws element offsets (unsigned short units) — sized, non-overlapping:
// Qo 2097152 | Kf 2097152 | Vf 2097152 | Wt 98304 | Em 16384  = 12.81 MB
#define OFF_Q  0u
#define OFF_K  2097152u
#define OFF_V  4194304u
#define OFF_W  6291456u
#define OFF_E  6389760u

// ---------------------------------------------------------------------------
// Kernel 0: W -> Wt (transposed, split bf16 hi/lo) + Em = exp2(mask*log2e) bf16
// grid (4,4,4), block 256.
// ---------------------------------------------------------------------------
__global__ __launch_bounds__(256) void wprep(
    const float* __restrict__ Wq, const float* __restrict__ Wk, const float* __restrict__ Wv,
    const float* __restrict__ maskg,
    unsigned short* __restrict__ Wt, unsigned short* __restrict__ Em)
{
    if (blockIdx.z == 3) {
        const int id16 = blockIdx.y * 4 + blockIdx.x;
        const int base = id16 * 1024 + threadIdx.x * 4;
        float4 m4 = *(const float4*)&maskg[base];
        ushort4 o;
        o.x = bf(__builtin_amdgcn_exp2f(m4.x * LOG2E));
        o.y = bf(__builtin_amdgcn_exp2f(m4.y * LOG2E));
        o.z = bf(__builtin_amdgcn_exp2f(m4.z * LOG2E));
        o.w = bf(__builtin_amdgcn_exp2f(m4.w * LOG2E));
        *(ushort4*)&Em[base] = o;
        return;
    }
    const float* W = (blockIdx.z == 0) ? Wq : (blockIdx.z == 1) ? Wk : Wv;
    unsigned short* Oh = Wt + (size_t)blockIdx.z * D_ * D_;
    unsigned short* Ol = Oh + 3 * D_ * D_;
    __shared__ float tf[32][36];
    const int t = threadIdx.x;
    const int kt = blockIdx.x * 32, ct = blockIdx.y * 32;
    {
        int kl = t >> 3, cl = (t & 7) * 4;
        float4 w4 = *(const float4*)&W[(size_t)(kt + kl) * D_ + ct + cl];
        tf[kl][cl + 0] = w4.x; tf[kl][cl + 1] = w4.y;
        tf[kl][cl + 2] = w4.z; tf[kl][cl + 3] = w4.w;
    }
    __syncthreads();
    {
        int cl = t >> 3, kl = (t & 7) * 4;
        ushort4 oh, ol;
        float v;
        v = tf[kl + 0][cl]; oh.x = bf(v); ol.x = bf(v - bf2f(oh.x));
        v = tf[kl + 1][cl]; oh.y = bf(v); ol.y = bf(v - bf2f(oh.y));
        v = tf[kl + 2][cl]; oh.z = bf(v); ol.z = bf(v - bf2f(oh.z));
        v = tf[kl + 3][cl]; oh.w = bf(v); ol.w = bf(v - bf2f(oh.w));
        *(ushort4*)&Oh[(size_t)(ct + cl) * D_ + kt + kl] = oh;
        *(ushort4*)&Ol[(size_t)(ct + cl) * D_ + kt + kl] = ol;
    }
}

// ---------------------------------------------------------------------------
// Kernel 1: QKV projection via split-bf16 MFMA (3 terms == fp32 accuracy).
// Q out: [bh][s][32] bf16 (pre-scaled by scale*log2e).
// K out: Kf fragment-native: [bh][kb32][fr(2)][lane(64)][8]
//        value K[kb32*32+(l&31)][fr*16+(l>>5)*8+e].
// V out: Vf fragment-native, em-scaled: [bh][kb16][lane(64)][8]
//        value V[kb16*16+(l>>5)*8+e][d=l&31]*em[key].
// grid (BS/32, 2 c-halves, 3 modes), block 256 = 4 waves.
// ---------------------------------------------------------------------------
__global__ __launch_bounds__(256) void qkv_mfma(
    const float* __restrict__ Xq, const float* __restrict__ Xk, const float* __restrict__ Xv,
    const unsigned short* __restrict__ Wt, const float* __restrict__ maskg,
    const float* __restrict__ bq, const float* __restrict__ bk, const float* __restrict__ bv,
    unsigned short* __restrict__ Qo, unsigned short* __restrict__ Kf,
    unsigned short* __restrict__ Vf)
{
    const int mode = blockIdx.z, chalf = blockIdx.y;
    const float* X; const float* bias; float scl;
    if (mode == 0)      { X = Xq; bias = bq; scl = QSCALE; }
    else if (mode == 1) { X = Xk; bias = bk; scl = 1.f; }
    else                { X = Xv; bias = bv; scl = 1.f; }
    const unsigned short* WmH = Wt + (size_t)mode * D_ * D_;
    const unsigned short* WmL = WmH + 3 * D_ * D_;

    __shared__ __align__(16) unsigned short xa[2 * 32 * 136];   // X hi/lo; reused as bounce
    __shared__ __align__(16) unsigned short wt[2 * 64 * 136];   // Wt hi/lo, 64 c-rows

    const int t = threadIdx.x;
    const long row0 = (long)blockIdx.x * 32;

    #pragma unroll
    for (int j = 0; j < 8; j++) {
        int idx = t + 256 * j;
        int part = idx >> 10, i2 = idx & 1023;
        int r = i2 >> 4, c16 = i2 & 15;
        const unsigned short* src = part ? WmL : WmH;
        uint4 v = *(const uint4*)&src[(size_t)(chalf * 64 + r) * D_ + c16 * 8];
        *(uint4*)&wt[part * 8704 + r * 136 + c16 * 8] = v;
    }
    #pragma unroll
    for (int j = 0; j < 4; j++) {
        int idx = t + 256 * j;
        int r = idx >> 5, c4 = idx & 31;
        float4 v = *(const float4*)(X + (row0 + r) * D_ + c4 * 4);
        ushort4 ph, pl;
        ph.x = bf(v.x); pl.x = bf(v.x - bf2f(ph.x));
        ph.y = bf(v.y); pl.y = bf(v.y - bf2f(ph.y));
        ph.z = bf(v.z); pl.z = bf(v.z - bf2f(ph.z));
        ph.w = bf(v.w); pl.w = bf(v.w - bf2f(ph.w));
        *(ushort4*)&xa[r * 136 + c4 * 4] = ph;
        *(ushort4*)&xa[4352 + r * 136 + c4 * 4] = pl;
    }
    __syncthreads();

    const int w = t >> 6, lane = t & 63, lo = lane & 15, hi = lane >> 4;
    const int mf = w >> 1, nb = (w & 1) * 2;
    f32x4 acc[2] = {};
    #pragma unroll
    for (int kk = 0; kk < 4; kk++) {
        const int ko = kk * 32 + hi * 8;
        s16x8 ah = *(const s16x8*)&xa[(mf * 16 + lo) * 136 + ko];
        s16x8 al = *(const s16x8*)&xa[4352 + (mf * 16 + lo) * 136 + ko];
        #pragma unroll
        for (int n2 = 0; n2 < 2; n2++) {
            const int nf = nb + n2;
            s16x8 bh2 = *(const s16x8*)&wt[(nf * 16 + lo) * 136 + ko];
            s16x8 bl2 = *(const s16x8*)&wt[8704 + (nf * 16 + lo) * 136 + ko];
            acc[n2] = __builtin_amdgcn_mfma_f32_16x16x32_bf16(ah, bh2, acc[n2], 0, 0, 0);
            acc[n2] = __builtin_amdgcn_mfma_f32_16x16x32_bf16(al, bh2, acc[n2], 0, 0, 0);
            acc[n2] = __builtin_amdgcn_mfma_f32_16x16x32_bf16(ah, bl2, acc[n2], 0, 0, 0);
        }
    }
    __syncthreads();   // xa free for bounce

    const long b_i = row0 >> 11;
    const long s0g = row0 & 2047;

    if (mode < 2) {
        #pragma unroll
        for (int n2 = 0; n2 < 2; n2++) {
            int c_l = (nb + n2) * 16 + lo;
            float bb = bias[chalf * 64 + c_l];
            #pragma unroll
            for (int r = 0; r < 4; r++) {
                int s = mf * 16 + hi * 4 + r;
                xa[s * 72 + c_l] = bf((acc[n2][r] + bb) * scl);
            }
        }
        __syncthreads();
        int s = t >> 3, part = t & 7;
        int c_g = chalf * 64 + part * 8;
        int h = c_g >> 5, dd = c_g & 31;
        long s_i = s0g + s;
        int bh = (int)(b_i * H_ + h);
        uint4 val = *(const uint4*)&xa[s * 72 + part * 8];
        if (mode == 0) {
            *(uint4*)(Qo + ((size_t)bh * S_ + s_i) * DH_ + dd) = val;
        } else {
            int fr = dd >> 4, hwd = (dd >> 3) & 1;
            size_t off = ((((size_t)bh * 64 + (s_i >> 5)) * 2 + fr) * 64
                          + (s_i & 31) + hwd * 32) * 8;
            *(uint4*)(Kf + off) = val;
        }
    } else {
        float emr[4];
        #pragma unroll
        for (int r = 0; r < 4; r++) {
            const int s_l = mf * 16 + hi * 4 + r;
            emr[r] = __builtin_amdgcn_exp2f(maskg[b_i * S_ + s0g + s_l] * LOG2E);
        }
        #pragma unroll
        for (int n2 = 0; n2 < 2; n2++) {
            int c_l = (nb + n2) * 16 + lo;
            float bb = bias[chalf * 64 + c_l];
            #pragma unroll
            for (int r = 0; r < 4; r++) {
                int s = mf * 16 + hi * 4 + r;
                xa[c_l * 68 + s] = bf((acc[n2][r] + bb) * emr[r]);
            }
        }
        __syncthreads();
        if (t < 128) {
            int c_l = t >> 1, sh2 = (t & 1) * 16;
            int c_g = chalf * 64 + c_l;
            int h = c_g >> 5, dd = c_g & 31;
            long key0 = s0g + sh2;
            int bh = (int)(b_i * H_ + h);
            size_t base = (((size_t)bh * 128 + (key0 >> 4)) * 64 + dd) * 8;
            uint2 p0 = *(const uint2*)&xa[c_l * 68 + sh2 + 0];
            uint2 p1 = *(const uint2*)&xa[c_l * 68 + sh2 + 4];
            uint2 p2 = *(const uint2*)&xa[c_l * 68 + sh2 + 8];
            uint2 p3 = *(const uint2*)&xa[c_l * 68 + sh2 + 12];
            *(uint4*)(Vf + base)       = make_uint4(p0.x, p0.y, p1.x, p1.y);  // keys 0-7 (hw=0)
            *(uint4*)(Vf + base + 256) = make_uint4(p2.x, p2.y, p3.x, p3.y);  // keys 8-15 (hw=1)
        }
    }
}

// ---------------------------------------------------------------------------
// Kernel 2: flash attention, 32x32x16 MFMA, LDS-free barrier-free inner loop.
// grid 2048 (32 bh x 64 q-tiles; 4 bh per XCD), block 256 = 4 waves.
// Wave w owns key quarter w of each 128-key tile. All K/V/em fragments are
// single coalesced b128 loads (fragment-native layouts). P stays in registers
// (cvt_pk + permlane32_swap). l via MFMA vs em-fragment. 4-way partial merge
// via LDS at the end (plain adds; no-max softmax partials are additive).
// ---------------------------------------------------------------------------
__global__ __launch_bounds__(256, 4) void flash_mfma(
    const unsigned short* __restrict__ Qg, const unsigned short* __restrict__ Kfg,
    const unsigned short* __restrict__ Vfg, const unsigned short* __restrict__ Emg,
    const float* __restrict__ head_mask, float* __restrict__ Out)
{
    __shared__ float ms[2][64][33];   // merge scratch: 2 slots x lane x 32 vals

    const int t = threadIdx.x, w = t >> 6, lane = t & 63;
    const int l31 = lane & 31, hw = lane >> 5;

    const int lid = blockIdx.x;
    const int xcd = lid & 7, ser = lid >> 3;          // blocks round-robin XCDs
    const int bh = xcd * 4 + (ser >> 6);              // 4 bh per XCD (32 total)
    const int qi = ser & 63;
    const int b = bh >> 2, h = bh & 3;
    const int q0 = qi * 32;

    // Q B-fragments (once per block)
    const unsigned short* qp = Qg + ((size_t)bh * S_ + q0 + l31) * DH_ + hw * 8;
    const s16x8 qf0 = *(const s16x8*)qp;
    const s16x8 qf1 = *(const s16x8*)(qp + 16);

    // wave-w fragment streams (keys tile*128 + w*32 .. +32)
    const unsigned short* kp = Kfg + (size_t)bh * 65536 + (size_t)w * 1024 + (size_t)lane * 8;
    const unsigned short* vp = Vfg + (size_t)bh * 65536 + (size_t)w * 1024 + (size_t)lane * 8;
    const unsigned short* ep = Emg + (size_t)b * S_ + w * 32 + hw * 8;

    s16x8 kf0 = *(const s16x8*)kp;
    s16x8 kf1 = *(const s16x8*)(kp + 512);
    s16x8 vf0 = *(const s16x8*)vp;
    s16x8 vf1 = *(const s16x8*)(vp + 512);

    f32x16 ctx = {}, lacc = {};
    const f32x16 z16 = {};

    for (int tile = 0; tile < 16; tile++) {
        s16x8 kn0, kn1, vn0, vn1;
        if (tile < 15) {   // prefetch next tile's fragments (coalesced b128)
            const unsigned short* kp2 = kp + (size_t)(tile + 1) * 4096;
            const unsigned short* vp2 = vp + (size_t)(tile + 1) * 4096;
            kn0 = *(const s16x8*)kp2;
            kn1 = *(const s16x8*)(kp2 + 512);
            vn0 = *(const s16x8*)vp2;
            vn1 = *(const s16x8*)(vp2 + 512);
        }
        const s16x8 ef0 = *(const s16x8*)(ep + tile * 128);
        const s16x8 ef1 = *(const s16x8*)(ep + tile * 128 + 16);

        // ---- QK^T (swapped): S^T[key][q], exp2 domain
        f32x16 s = __builtin_amdgcn_mfma_f32_32x32x16_bf16(kf0, qf0, z16, 0, 0, 0);
        s = __builtin_amdgcn_mfma_f32_32x32x16_bf16(kf1, qf1, s, 0, 0, 0);

        // ---- P = exp2(s), pack (1 cvt_pk each), permlane into PV A-frags
        unsigned int pd[8];
        #pragma unroll
        for (int j = 0; j < 8; j++) {
            const float p0 = __builtin_amdgcn_exp2f(s[2 * j]);
            const float p1 = __builtin_amdgcn_exp2f(s[2 * j + 1]);
            pd[j] = pk2(p0, p1);
        }
        pswap(pd[0], pd[2]); pswap(pd[1], pd[3]);
        pswap(pd[4], pd[6]); pswap(pd[5], pd[7]);
        const s16x8 pa0 = __builtin_bit_cast(s16x8, make_uint4(pd[0], pd[1], pd[2], pd[3]));
        const s16x8 pa1 = __builtin_bit_cast(s16x8, make_uint4(pd[4], pd[5], pd[6], pd[7]));

        // ---- PV + l
        ctx  = __builtin_amdgcn_mfma_f32_32x32x16_bf16(pa0, vf0, ctx, 0, 0, 0);
        lacc = __builtin_amdgcn_mfma_f32_32x32x16_bf16(pa0, ef0, lacc, 0, 0, 0);
        ctx  = __builtin_amdgcn_mfma_f32_32x32x16_bf16(pa1, vf1, ctx, 0, 0, 0);
        lacc = __builtin_amdgcn_mfma_f32_32x32x16_bf16(pa1, ef1, lacc, 0, 0, 0);

        if (tile < 15) { kf0 = kn0; kf1 = kn1; vf0 = vn0; vf1 = vn1; }
    }

    // ---- 4-way key-split merge (partials are additive: no-max softmax)
    if (w >= 2) {
        float* d = &ms[w - 2][lane][0];
        #pragma unroll
        for (int r = 0; r < 16; r++) { d[r] = ctx[r]; d[16 + r] = lacc[r]; }
    }
    __syncthreads();
    if (w < 2) {
        const float* sr = &ms[w][lane][0];
        #pragma unroll
        for (int r = 0; r < 16; r++) { ctx[r] += sr[r]; lacc[r] += sr[16 + r]; }
    }
    __syncthreads();
    if (w == 1) {
        float* d = &ms[0][lane][0];
        #pragma unroll
        for (int r = 0; r < 16; r++) { d[r] = ctx[r]; d[16 + r] = lacc[r]; }
    }
    __syncthreads();
    if (w == 0) {
        const float* sr = &ms[0][lane][0];
        #pragma unroll
        for (int r = 0; r < 16; r++) { ctx[r] += sr[r]; lacc[r] += sr[16 + r]; }
        const float hm = head_mask[h];
        #pragma unroll
        for (int r = 0; r < 16; r++) {
            const int qrow = (r & 3) + 8 * (r >> 2) + 4 * hw;
            Out[((size_t)b * S_ + q0 + qrow) * D_ + h * DH_ + l31] = ctx[r] * hm / lacc[r];
        }
    }
}

// ---------------------------------------------------------------------------
extern "C" void kernel_launch(void* const* d_in, const int* in_sizes, int n_in,
                              void* d_out, int out_size, void* d_ws, size_t ws_size,
                              hipStream_t stream) {
    const float* Xq   = (const float*)d_in[0];
    const float* Xk   = (const float*)d_in[1];
    const float* Xv   = (const float*)d_in[2];
    const float* mask = (const float*)d_in[3];
    const float* hm   = (const float*)d_in[4];
    const float* Wq   = (const float*)d_in[5];
    const float* bq   = (const float*)d_in[6];
    const float* Wk   = (const float*)d_in[7];
    const float* bk   = (const float*)d_in[8];
    const float* Wv   = (const float*)d_in[9];
    const float* bv   = (const float*)d_in[10];
    float* out = (float*)d_out;

    unsigned short* ws = (unsigned short*)d_ws;
    unsigned short* Qo = ws + OFF_Q;    // [bh][s][32] bf16
    unsigned short* Kf = ws + OFF_K;    // frag-native K
    unsigned short* Vf = ws + OFF_V;    // frag-native V (em-scaled)
    unsigned short* Wt = ws + OFF_W;    // [2][3][128][128] split bf16
    unsigned short* Em = ws + OFF_E;    // [b][s] bf16 exp(mask)

    wprep<<<dim3(4, 4, 4), 256, 0, stream>>>(Wq, Wk, Wv, mask, Wt, Em);
    qkv_mfma<<<dim3(BS_ / 32, 2, 3), 256, 0, stream>>>(Xq, Xk, Xv, Wt, mask,
                                                       bq, bk, bv, Qo, Kf, Vf);
    flash_mfma<<<dim3(2048), 256, 0, stream>>>(Qo, Kf, Vf, Em, hm, out);
}